// Round 9
// baseline (193.207 us; speedup 1.0000x reference)
//
#include <hip/hip_runtime.h>
#include <hip/hip_bf16.h>
#include <math.h>

#define B 2
#define N 2048
#define D 1024
#define H 16
#define HD 64

typedef __attribute__((ext_vector_type(8))) short short8;
typedef __attribute__((ext_vector_type(4))) float f32x4;
typedef __attribute__((ext_vector_type(16))) float f32x16;
typedef __attribute__((ext_vector_type(4))) unsigned short ush4;
typedef __attribute__((ext_vector_type(4))) unsigned int uint4v;

__device__ __forceinline__ float bf2f(unsigned short u) {
  unsigned int x = ((unsigned int)u) << 16;
  float f;
  __builtin_memcpy(&f, &x, 4);
  return f;
}
__device__ __forceinline__ unsigned short f2bf(float f) {
  unsigned int x;
  __builtin_memcpy(&x, &f, 4);
  x = x + 0x7fffu + ((x >> 16) & 1u);
  return (unsigned short)(x >> 16);
}
__device__ __forceinline__ unsigned int pk2(float lo, float hi) {
  union { __hip_bfloat162 h; unsigned int u; } cv;
  cv.h = __float22bfloat162_rn(make_float2(lo, hi));
  return cv.u;
}
__device__ __forceinline__ short8 mk_frag(unsigned int w0, unsigned int w1,
                                          unsigned int w2, unsigned int w3) {
  union { uint4v u; short8 s; } cv;
  cv.u = (uint4v){w0, w1, w2, w3};
  return cv.s;
}

// async global->LDS, 16B per lane (GEMM staging only).
__device__ __forceinline__ void gload16(const unsigned short* g, unsigned short* l) {
  __builtin_amdgcn_global_load_lds(
      (const __attribute__((address_space(1))) unsigned int*)(const void*)g,
      (__attribute__((address_space(3))) unsigned int*)(void*)l, 16, 0, 0);
}

// ---------- prep: weight conversions + rope table in ONE launch ----------
__global__ void prep_k(const float* __restrict__ wqkv, unsigned short* __restrict__ wqkv_bf,
                       const float* __restrict__ wout, unsigned short* __restrict__ wout_bf,
                       float2* __restrict__ tab) {
  int blk = blockIdx.x;
  if (blk < 4096) {
    const float* src = (blk < 3072) ? wqkv : wout;
    unsigned short* dst = (blk < 3072) ? wqkv_bf : wout_bf;
    int i = (blk < 3072 ? blk : blk - 3072) * 256 + threadIdx.x;
    float4 v = ((const float4*)src)[i];
    ush4 o;
    o[0] = f2bf(v.x); o[1] = f2bf(v.y); o[2] = f2bf(v.z); o[3] = f2bf(v.w);
    *(ush4*)&dst[i * 4] = o;
  } else {
    int idx = (blk - 4096) * 256 + threadIdx.x;  // 2048*32
    int t = idx >> 5, p = idx & 31;
    float inv = powf(10000.f, -(float)p / 32.f);
    float ang = (float)t * inv;
    float s, c;
    sincosf(ang, &s, &c);
    tab[idx] = make_float2(c, s);
  }
}

// x (B, D, N) f32 -> xt (B, N, D) bf16
__global__ __launch_bounds__(256) void transpose_x(const float* __restrict__ x,
                                                   unsigned short* __restrict__ xt) {
  __shared__ float tile[32][33];
  const int tx = threadIdx.x, ty = threadIdx.y;
  const int t0 = blockIdx.x * 32, d0 = blockIdx.y * 32, bb = blockIdx.z;
#pragma unroll
  for (int i = 0; i < 4; ++i) {
    int r = ty * 4 + i;
    tile[r][tx] = x[(size_t)bb * D * N + (size_t)(d0 + r) * N + t0 + tx];
  }
  __syncthreads();
#pragma unroll
  for (int i = 0; i < 4; ++i) {
    int r = ty * 4 + i;
    xt[((size_t)(bb * N) + t0 + r) * D + d0 + tx] = f2bf(tile[tx][r]);
  }
}

// ---------- GEMM: C[m][n] = sum_k A[m][k] * Bt[n][k], both K-contiguous bf16 ----------
// 128x128 tile, BK=64, 4 waves (2x2), wave = 64x64 (4x4 fragments of 16x16x32).
// MODE 0: qkv projection epilogue -> q/k token-major into qkbuf, v transposed into vtbuf.
// MODE 1: final projection epilogue -> f32 out (B, D, N).
template <int MODE>
__global__ __launch_bounds__(256) void gemm_bt(const unsigned short* __restrict__ A,
                                               const unsigned short* __restrict__ Bt,
                                               float* __restrict__ outf,
                                               unsigned short* __restrict__ qkbuf,
                                               unsigned short* __restrict__ vtbuf) {
  __shared__ unsigned short Asm[128 * 64];
  __shared__ unsigned short Bsm[128 * 64];
  const int tid = threadIdx.x;
  const int lane = tid & 63, wid = tid >> 6;
  const int ln = lane & 15, lh = lane >> 4;
  const int wr = wid >> 1, wc = wid & 1;
  const int m0 = blockIdx.x * 128, n0 = blockIdx.y * 128;

  f32x4 acc[4][4];
#pragma unroll
  for (int i = 0; i < 4; ++i)
#pragma unroll
    for (int j = 0; j < 4; ++j) acc[i][j] = (f32x4){0.f, 0.f, 0.f, 0.f};

  for (int k0 = 0; k0 < 1024; k0 += 64) {
#pragma unroll
    for (int jj = 0; jj < 4; ++jj) {
      int slot = tid + jj * 256;
      int row = slot >> 3, u = slot & 7;
      int usw = (u ^ (row & 7)) * 8;
      gload16(&A[(size_t)(m0 + row) * 1024 + k0 + usw], &Asm[slot * 8]);
    }
#pragma unroll
    for (int jj = 0; jj < 4; ++jj) {
      int slot = tid + jj * 256;
      int row = slot >> 3, u = slot & 7;
      int usw = (u ^ (row & 7)) * 8;
      gload16(&Bt[(size_t)(n0 + row) * 1024 + k0 + usw], &Bsm[slot * 8]);
    }
    __syncthreads();
#pragma unroll
    for (int s = 0; s < 2; ++s) {
      short8 af[4], bfr[4];
#pragma unroll
      for (int i = 0; i < 4; ++i) {
        int row = wr * 64 + i * 16 + ln;
        int u = ((s * 4 + lh) ^ (row & 7)) * 8;
        af[i] = *(const short8*)&Asm[row * 64 + u];
      }
#pragma unroll
      for (int j = 0; j < 4; ++j) {
        int row = wc * 64 + j * 16 + ln;
        int u = ((s * 4 + lh) ^ (row & 7)) * 8;
        bfr[j] = *(const short8*)&Bsm[row * 64 + u];
      }
#pragma unroll
      for (int i = 0; i < 4; ++i)
#pragma unroll
        for (int j = 0; j < 4; ++j)
          acc[i][j] = __builtin_amdgcn_mfma_f32_16x16x32_bf16(af[i], bfr[j], acc[i][j], 0, 0, 0);
    }
    __syncthreads();
  }

#pragma unroll
  for (int i = 0; i < 4; ++i) {
    int mrow = m0 + wr * 64 + i * 16 + lh * 4;
    int bb = mrow >> 11, t = mrow & 2047;
#pragma unroll
    for (int j = 0; j < 4; ++j) {
      int e = n0 + wc * 64 + j * 16 + ln;
      if (MODE == 1) {
        float* op = outf + (size_t)bb * D * N + (size_t)e * N + t;
        *(f32x4*)op = acc[i][j];
      } else {
        if (e < 2048) {
#pragma unroll
          for (int jj = 0; jj < 4; ++jj)
            qkbuf[((size_t)(bb * N + t + jj)) * 2048 + e] = f2bf(acc[i][j][jj]);
        } else {
          ush4 v;
#pragma unroll
          for (int jj = 0; jj < 4; ++jj) v[jj] = f2bf(acc[i][j][jj]);
          *(ush4*)&vtbuf[((size_t)bb * 1024 + (e - 2048)) * N + t] = v;
        }
      }
    }
  }
}

// ---------- RoPE in place on qkbuf (B, N, 2048) bf16, pairs adjacent ----------
// Folds 0.125*log2e into the q section so attention uses exp2 with no scaling.
__global__ void rope_kernel(unsigned short* __restrict__ qk, const float2* __restrict__ tab) {
  int idx = blockIdx.x * 256 + threadIdx.x;  // B*N*2048/8 = 1,048,576
  int e = (idx & 255) * 8;
  int t = (idx >> 8) & 2047;
  int bb = idx >> 19;
  int p0 = (e & 63) >> 1;
  const float qscl = 0.125f * 1.4426950408889634f;  // hd^-0.5 * log2(e)
  float sc = (e < 1024) ? qscl : 1.0f;
  unsigned short* p = qk + ((size_t)(bb * N + t)) * 2048 + e;
  short8 v = *(short8*)p;
#pragma unroll
  for (int q = 0; q < 4; ++q) {
    float2 cs = tab[t * 32 + p0 + q];
    float xe = bf2f((unsigned short)v[2 * q]);
    float xo = bf2f((unsigned short)v[2 * q + 1]);
    v[2 * q] = (short)f2bf((xe * cs.x - xo * cs.y) * sc);
    v[2 * q + 1] = (short)f2bf((xe * cs.y + xo * cs.x) * sc);
  }
  *(short8*)p = v;
}

// ---------- flash attention: NO-LDS direct-from-L2 fragments ----------
// Every MFMA operand is 16B-contiguous in global memory: K (token-major) is
// d-contiguous; vt (d-major) is key-contiguous. Load fragments global->VGPR,
// no LDS, no barriers, no staging. 4 waves/block re-read each tile from L2
// (~1 GB total over L2 at ~25 TB/s); per-XCD working set = 4 heads' K/V
// = 2 MB < 4 MB L2 (hh = L&31 keeps a head's 16 blocks on one XCD).
// K is reg-double-buffered (K(t+1) issued before TILE(t)); V issues at
// iteration top and is consumed ~300cy later (covers L2 latency).
// STATIC-MAX softmax as before. qk: (B,N,2048) (q pre-scaled); vt: (B,1024,N).
__global__ __launch_bounds__(256, 2) void attn_kernel(const unsigned short* __restrict__ qk,
                                                      const unsigned short* __restrict__ vt,
                                                      unsigned short* __restrict__ ob) {
  const int tid = threadIdx.x;
  const int lane = tid & 63, wid = tid >> 6;
  const int l31 = lane & 31, hi = lane >> 5;
  const int L = blockIdx.x;
  const int hh = L & 31, qb = L >> 5;
  const int bb = hh >> 4, h = hh & 15;
  const unsigned short* Qg = qk + (size_t)bb * N * 2048 + h * 64;
  const unsigned short* Kg = Qg + 1024;
  const unsigned short* Vg = vt + ((size_t)bb * 1024 + h * 64) * N;

  const int q = qb * 128 + wid * 32 + l31;
  // Q as B-fragments: lane holds q-col, k(d) = c*16 + hi*8 + j
  short8 qf[4];
#pragma unroll
  for (int c = 0; c < 4; ++c)
    qf[c] = *(const short8*)&Qg[(size_t)q * 2048 + c * 16 + hi * 8];

  // per-lane K row bases (rows l31 and 32+l31 of each tile), d-offset hi*8
  const unsigned short* KrowA = Kg + (size_t)l31 * 2048 + hi * 8;
  const unsigned short* KrowB = Kg + (size_t)(32 + l31) * 2048 + hi * 8;
  // per-lane V row bases (d-rows l31 and 32+l31), key-offset hi*8
  const unsigned short* VrowA = Vg + (size_t)l31 * N + hi * 8;
  const unsigned short* VrowB = Vg + (size_t)(32 + l31) * N + hi * 8;

  f32x16 oL, oH;
#pragma unroll
  for (int r = 0; r < 16; ++r) { oL[r] = 0.f; oH[r] = 0.f; }
  float lrun = 0.f;

  auto LDK = [&](short8* kf, int kb) {
    const unsigned short* pa = KrowA + (size_t)kb * 2048;
    const unsigned short* pb = KrowB + (size_t)kb * 2048;
#pragma unroll
    for (int c = 0; c < 4; ++c) {
      kf[c] = *(const short8*)(pa + c * 16);      // d = (2c+hi)*8 .. +8
      kf[4 + c] = *(const short8*)(pb + c * 16);
    }
  };
  auto LDV = [&](short8* vf, int kb) {
    const unsigned short* pa = VrowA + kb;
    const unsigned short* pb = VrowB + kb;
#pragma unroll
    for (int c = 0; c < 4; ++c) {
      vf[c] = *(const short8*)(pa + c * 16);      // keys (2c+hi)*8 .. +8
      vf[4 + c] = *(const short8*)(pb + c * 16);
    }
  };

  auto TILE = [&](const short8* kf, const short8* vf) {
    f32x16 s0, s1;
#pragma unroll
    for (int r = 0; r < 16; ++r) { s0[r] = 0.f; s1[r] = 0.f; }
    __builtin_amdgcn_s_setprio(1);
#pragma unroll
    for (int c = 0; c < 4; ++c) {
      s0 = __builtin_amdgcn_mfma_f32_32x32x16_bf16(kf[c], qf[c], s0, 0, 0, 0);
      s1 = __builtin_amdgcn_mfma_f32_32x32x16_bf16(kf[4 + c], qf[c], s1, 0, 0, 0);
    }
    __builtin_amdgcn_s_setprio(0);
    float lsum = 0.f;
#pragma unroll
    for (int r = 0; r < 16; ++r) {
      s0[r] = __builtin_amdgcn_exp2f(s0[r]);
      s1[r] = __builtin_amdgcn_exp2f(s1[r]);
      lsum += s0[r] + s1[r];
    }
    lrun += lsum;
    unsigned int W[16];
#pragma unroll
    for (int i = 0; i < 8; ++i) {
      W[i] = pk2(s0[2 * i], s0[2 * i + 1]);
      W[8 + i] = pk2(s1[2 * i], s1[2 * i + 1]);
    }
    short8 pf[4];
#pragma unroll
    for (int c = 0; c < 4; ++c) {
      unsigned int a0 = W[4 * c + 0], b0 = W[4 * c + 2];
      unsigned int a1 = W[4 * c + 1], b1 = W[4 * c + 3];
      asm volatile("v_permlane32_swap_b32 %0, %1" : "+v"(a0), "+v"(b0));
      asm volatile("v_permlane32_swap_b32 %0, %1" : "+v"(a1), "+v"(b1));
      pf[c] = mk_frag(a0, a1, b0, b1);
    }
    __builtin_amdgcn_s_setprio(1);
#pragma unroll
    for (int c = 0; c < 4; ++c) {
      oL = __builtin_amdgcn_mfma_f32_32x32x16_bf16(vf[c], pf[c], oL, 0, 0, 0);
      oH = __builtin_amdgcn_mfma_f32_32x32x16_bf16(vf[4 + c], pf[c], oH, 0, 0, 0);
    }
    __builtin_amdgcn_s_setprio(0);
  };

  // K ping-pong in registers; V loaded per half-iteration.
  short8 kA[8], kB[8], vf[8];
  LDK(kA, 0);
  for (int tt = 0; tt < 32; tt += 2) {
    LDK(kB, (tt + 1) * 64);          // next K issued before this tile's compute
    LDV(vf, tt * 64);                // V for this tile (consumed after exp/pack)
    TILE(kA, vf);
    if (tt + 2 < 32) LDK(kA, (tt + 2) * 64);
    LDV(vf, (tt + 1) * 64);
    TILE(kB, vf);
  }

  // final l reduce (partner lane holds the other 32 keys of every tile)
  lrun += __shfl_xor(lrun, 32, 64);
  float inv = 1.f / lrun;
  unsigned short* obp = ob + ((size_t)(bb * N + q)) * 1024 + h * 64;
#pragma unroll
  for (int r4 = 0; r4 < 4; ++r4) {
    ush4 vL, vH;
#pragma unroll
    for (int i = 0; i < 4; ++i) {
      vL[i] = f2bf(oL[r4 * 4 + i] * inv);
      vH[i] = f2bf(oH[r4 * 4 + i] * inv);
    }
    *(ush4*)&obp[r4 * 8 + hi * 4] = vL;
    *(ush4*)&obp[32 + r4 * 8 + hi * 4] = vH;
  }
}

extern "C" void kernel_launch(void* const* d_in, const int* in_sizes, int n_in,
                              void* d_out, int out_size, void* d_ws, size_t ws_size,
                              hipStream_t stream) {
  const float* x = (const float*)d_in[0];
  const float* w_qkv = (const float*)d_in[1];
  const float* w_out = (const float*)d_in[2];
  float* out = (float*)d_out;
  char* ws = (char*)d_ws;

  unsigned short* wqkv_bf = (unsigned short*)ws;                    // 6 MB
  unsigned short* wout_bf = (unsigned short*)(ws + 6291456);        // 2 MB
  unsigned short* xt      = (unsigned short*)(ws + 8388608);        // 8 MB (reused as obuf)
  unsigned short* qkbuf   = (unsigned short*)(ws + 16777216);       // 16 MB
  unsigned short* vtbuf   = (unsigned short*)(ws + 33554432);       // 8 MB
  float2* tab             = (float2*)(ws + 41943040);               // 0.5 MB

  prep_k<<<4352, 256, 0, stream>>>(w_qkv, wqkv_bf, w_out, wout_bf, tab);
  transpose_x<<<dim3(N / 32, D / 32, B), dim3(32, 8), 0, stream>>>(x, xt);

  gemm_bt<0><<<dim3(32, 24), 256, 0, stream>>>(xt, wqkv_bf, nullptr, qkbuf, vtbuf);
  rope_kernel<<<4096, 256, 0, stream>>>(qkbuf, tab);
  attn_kernel<<<512, 256, 0, stream>>>(qkbuf, vtbuf, xt /* obuf */);
  gemm_bt<1><<<dim3(32, 8), 256, 0, stream>>>(xt, wout_bf, out, nullptr, nullptr);
}

// Round 10
// 128.679 us; speedup vs baseline: 1.5015x; 1.5015x over previous
//
#include <hip/hip_runtime.h>
#include <hip/hip_bf16.h>
#include <math.h>

#define B 2
#define N 2048
#define D 1024
#define H 16
#define HD 64

typedef __attribute__((ext_vector_type(8))) short short8;
typedef __attribute__((ext_vector_type(8))) unsigned short ush8;
typedef __attribute__((ext_vector_type(4))) float f32x4;
typedef __attribute__((ext_vector_type(16))) float f32x16;
typedef __attribute__((ext_vector_type(4))) unsigned short ush4;
typedef __attribute__((ext_vector_type(4))) unsigned int uint4v;

__device__ __forceinline__ float bf2f(unsigned short u) {
  unsigned int x = ((unsigned int)u) << 16;
  float f;
  __builtin_memcpy(&f, &x, 4);
  return f;
}
__device__ __forceinline__ unsigned short f2bf(float f) {
  unsigned int x;
  __builtin_memcpy(&x, &f, 4);
  x = x + 0x7fffu + ((x >> 16) & 1u);
  return (unsigned short)(x >> 16);
}
__device__ __forceinline__ unsigned int pk2(float lo, float hi) {
  union { __hip_bfloat162 h; unsigned int u; } cv;
  cv.h = __float22bfloat162_rn(make_float2(lo, hi));
  return cv.u;
}
__device__ __forceinline__ short8 mk_frag(unsigned int w0, unsigned int w1,
                                          unsigned int w2, unsigned int w3) {
  union { uint4v u; short8 s; } cv;
  cv.u = (uint4v){w0, w1, w2, w3};
  return cv.s;
}

// async global->LDS, 16B per lane. LDS dest linear (base + lane*16);
// swizzle lives in the per-lane GLOBAL address (m173/m201 pattern).
__device__ __forceinline__ void gload16(const unsigned short* g, unsigned short* l) {
  __builtin_amdgcn_global_load_lds(
      (const __attribute__((address_space(1))) unsigned int*)(const void*)g,
      (__attribute__((address_space(3))) unsigned int*)(void*)l, 16, 0, 0);
}

// ---------- prep: weight conversions + rope table in ONE launch ----------
__global__ void prep_k(const float* __restrict__ wqkv, unsigned short* __restrict__ wqkv_bf,
                       const float* __restrict__ wout, unsigned short* __restrict__ wout_bf,
                       float2* __restrict__ tab) {
  int blk = blockIdx.x;
  if (blk < 4096) {
    const float* src = (blk < 3072) ? wqkv : wout;
    unsigned short* dst = (blk < 3072) ? wqkv_bf : wout_bf;
    int i = (blk < 3072 ? blk : blk - 3072) * 256 + threadIdx.x;
    float4 v = ((const float4*)src)[i];
    ush4 o;
    o[0] = f2bf(v.x); o[1] = f2bf(v.y); o[2] = f2bf(v.z); o[3] = f2bf(v.w);
    *(ush4*)&dst[i * 4] = o;
  } else {
    int idx = (blk - 4096) * 256 + threadIdx.x;  // 2048*32
    int t = idx >> 5, p = idx & 31;
    float inv = powf(10000.f, -(float)p / 32.f);
    float ang = (float)t * inv;
    float s, c;
    sincosf(ang, &s, &c);
    tab[idx] = make_float2(c, s);
  }
}

// x (B, D, N) f32 -> xt (B, N, D) bf16
__global__ __launch_bounds__(256) void transpose_x(const float* __restrict__ x,
                                                   unsigned short* __restrict__ xt) {
  __shared__ float tile[32][33];
  const int tx = threadIdx.x, ty = threadIdx.y;
  const int t0 = blockIdx.x * 32, d0 = blockIdx.y * 32, bb = blockIdx.z;
#pragma unroll
  for (int i = 0; i < 4; ++i) {
    int r = ty * 4 + i;
    tile[r][tx] = x[(size_t)bb * D * N + (size_t)(d0 + r) * N + t0 + tx];
  }
  __syncthreads();
#pragma unroll
  for (int i = 0; i < 4; ++i) {
    int r = ty * 4 + i;
    xt[((size_t)(bb * N) + t0 + r) * D + d0 + tx] = f2bf(tile[tx][r]);
  }
}

// ---------- GEMM: C[m][n] = sum_k A[m][k] * Bt[n][k], both K-contiguous bf16 ----------
// 128x128 tile, BK=64, 4 waves (2x2), wave = 64x64 (4x4 fragments of 16x16x32).
// MODE 0: qkv projection. Q/K blocks (n0<2048): LDS-transpose epilogue with
//   FUSED RoPE (+q scale) -> coalesced 16B stores to qkbuf token-major.
//   V blocks (n0>=2048): direct vectorized stores to vtbuf d-major.
// MODE 1: final projection epilogue -> f32 out (B, D, N).
template <int MODE>
__global__ __launch_bounds__(256) void gemm_bt(const unsigned short* __restrict__ A,
                                               const unsigned short* __restrict__ Bt,
                                               float* __restrict__ outf,
                                               unsigned short* __restrict__ qkbuf,
                                               unsigned short* __restrict__ vtbuf,
                                               const float2* __restrict__ tab) {
  __shared__ __align__(16) unsigned short smem_all[128 * 128];  // 32 KB
  unsigned short* Asm = smem_all;              // [128 rows][64 k] (16 KB)
  unsigned short* Bsm = smem_all + 128 * 64;   // [128 rows][64 k] (16 KB)
  const int tid = threadIdx.x;
  const int lane = tid & 63, wid = tid >> 6;
  const int ln = lane & 15, lh = lane >> 4;
  const int wr = wid >> 1, wc = wid & 1;
  const int m0 = blockIdx.x * 128, n0 = blockIdx.y * 128;

  f32x4 acc[4][4];
#pragma unroll
  for (int i = 0; i < 4; ++i)
#pragma unroll
    for (int j = 0; j < 4; ++j) acc[i][j] = (f32x4){0.f, 0.f, 0.f, 0.f};

  for (int k0 = 0; k0 < 1024; k0 += 64) {
#pragma unroll
    for (int jj = 0; jj < 4; ++jj) {
      int slot = tid + jj * 256;
      int row = slot >> 3, u = slot & 7;
      int usw = (u ^ (row & 7)) * 8;
      gload16(&A[(size_t)(m0 + row) * 1024 + k0 + usw], &Asm[slot * 8]);
    }
#pragma unroll
    for (int jj = 0; jj < 4; ++jj) {
      int slot = tid + jj * 256;
      int row = slot >> 3, u = slot & 7;
      int usw = (u ^ (row & 7)) * 8;
      gload16(&Bt[(size_t)(n0 + row) * 1024 + k0 + usw], &Bsm[slot * 8]);
    }
    __syncthreads();
#pragma unroll
    for (int s = 0; s < 2; ++s) {
      short8 af[4], bfr[4];
#pragma unroll
      for (int i = 0; i < 4; ++i) {
        int row = wr * 64 + i * 16 + ln;
        int u = ((s * 4 + lh) ^ (row & 7)) * 8;
        af[i] = *(const short8*)&Asm[row * 64 + u];
      }
#pragma unroll
      for (int j = 0; j < 4; ++j) {
        int row = wc * 64 + j * 16 + ln;
        int u = ((s * 4 + lh) ^ (row & 7)) * 8;
        bfr[j] = *(const short8*)&Bsm[row * 64 + u];
      }
#pragma unroll
      for (int i = 0; i < 4; ++i)
#pragma unroll
        for (int j = 0; j < 4; ++j)
          acc[i][j] = __builtin_amdgcn_mfma_f32_16x16x32_bf16(af[i], bfr[j], acc[i][j], 0, 0, 0);
    }
    __syncthreads();  // all LDS reads done -> safe to alias smem_all below
  }

  if (MODE == 0 && n0 < 2048) {
    // ---- Q/K: LDS transpose epilogue + fused RoPE ----
    // Csm: 128x128 bf16, physical 16B-chunk = (e>>3) ^ (r&15)  (conflict-free
    // by 8-lane-phase construction on both write and read).
    unsigned short* Csm = smem_all;
#pragma unroll
    for (int i = 0; i < 4; ++i) {
      int rb = wr * 64 + i * 16 + lh * 4;
#pragma unroll
      for (int j = 0; j < 4; ++j) {
        int e = wc * 64 + j * 16 + ln;
        int c = e >> 3, o = e & 7;
#pragma unroll
        for (int jj = 0; jj < 4; ++jj) {
          int rr = rb + jj;
          Csm[rr * 128 + ((c ^ (rr & 15)) * 8) + o] = f2bf(acc[i][j][jj]);
        }
      }
    }
    __syncthreads();
    const int bb = m0 >> 11, tbase = m0 & 2047;
    const float sc = (n0 < 1024) ? 0.125f * 1.4426950408889634f : 1.0f;  // q: hd^-0.5*log2e
    const int c16 = tid & 15, rgrp = tid >> 4;
    const int p0 = (c16 & 7) * 4;
#pragma unroll
    for (int pass = 0; pass < 8; ++pass) {
      int r = rgrp + pass * 16;               // r & 15 == rgrp
      int t = tbase + r;
      ush8 v = *(const ush8*)&Csm[r * 128 + ((c16 ^ rgrp) * 8)];
#pragma unroll
      for (int k = 0; k < 4; ++k) {
        float2 cs = tab[t * 32 + p0 + k];
        float xe = bf2f(v[2 * k]), xo = bf2f(v[2 * k + 1]);
        v[2 * k]     = f2bf((xe * cs.x - xo * cs.y) * sc);
        v[2 * k + 1] = f2bf((xe * cs.y + xo * cs.x) * sc);
      }
      *(ush8*)&qkbuf[((size_t)(bb * N + t)) * 2048 + n0 + c16 * 8] = v;
    }
  } else {
#pragma unroll
    for (int i = 0; i < 4; ++i) {
      int mrow = m0 + wr * 64 + i * 16 + lh * 4;
      int bb = mrow >> 11, t = mrow & 2047;
#pragma unroll
      for (int j = 0; j < 4; ++j) {
        int e = n0 + wc * 64 + j * 16 + ln;
        if (MODE == 1) {
          float* op = outf + (size_t)bb * D * N + (size_t)e * N + t;
          *(f32x4*)op = acc[i][j];
        } else {
          ush4 v;
#pragma unroll
          for (int jj = 0; jj < 4; ++jj) v[jj] = f2bf(acc[i][j][jj]);
          *(ush4*)&vtbuf[((size_t)bb * 1024 + (e - 2048)) * N + t] = v;
        }
      }
    }
  }
}

// ---------- flash attention: swapped-operand 32x32 MFMA, P in registers ----------
// STATIC-MAX softmax (logits bounded; P = exp2(s) directly, l a plain sum).
// R4 structure verbatim (proven 55.4 us): 2-buf LDS, one syncthreads/iter.
// qk: (B, N, 2048) bf16 (q pre-scaled by 0.125*log2e); vt: (B, 1024, N) bf16.
__global__ __launch_bounds__(256, 2) void attn_kernel(const unsigned short* __restrict__ qk,
                                                      const unsigned short* __restrict__ vt,
                                                      unsigned short* __restrict__ ob) {
  __shared__ unsigned short Ksm[2][64 * 64];  // [key][d]
  __shared__ unsigned short Vsm[2][64 * 64];  // [d][key]
  const int tid = threadIdx.x;
  const int lane = tid & 63, wid = tid >> 6;
  const int l31 = lane & 31, hi = lane >> 5;
  const int L = blockIdx.x;
  const int hh = L & 31, qb = L >> 5;
  const int bb = hh >> 4, h = hh & 15;
  const unsigned short* Qg = qk + (size_t)bb * N * 2048 + h * 64;
  const unsigned short* Kg = Qg + 1024;
  const unsigned short* Vg = vt + ((size_t)bb * 1024 + h * 64) * N;

  const int q = qb * 128 + wid * 32 + l31;
  short8 qf[4];
#pragma unroll
  for (int c = 0; c < 4; ++c)
    qf[c] = *(const short8*)&Qg[(size_t)q * 2048 + c * 16 + hi * 8];

  f32x16 oL, oH;
#pragma unroll
  for (int r = 0; r < 16; ++r) { oL[r] = 0.f; oH[r] = 0.f; }
  float lrun = 0.f;

  auto STAGE = [&](int buf, int kb) {
#pragma unroll
    for (int jj = 0; jj < 2; ++jj) {
      int slot = tid + jj * 256;
      int row = slot >> 3, u = slot & 7;
      int usw = (u ^ (row & 7)) * 8;
      gload16(&Kg[(size_t)(kb + row) * 2048 + usw], &Ksm[buf][slot * 8]);
    }
#pragma unroll
    for (int jj = 0; jj < 2; ++jj) {
      int slot = tid + jj * 256;
      int row = slot >> 3, u = slot & 7;
      int usw = (u ^ (row & 7)) * 8;
      gload16(&Vg[(size_t)row * N + kb + usw], &Vsm[buf][slot * 8]);
    }
  };

  STAGE(0, 0);
  __syncthreads();
  int cur = 0;
  for (int t = 0; t < N / 64; ++t) {
    if (t < N / 64 - 1) STAGE(cur ^ 1, (t + 1) * 64);
    f32x16 s0, s1;
#pragma unroll
    for (int r = 0; r < 16; ++r) { s0[r] = 0.f; s1[r] = 0.f; }
    __builtin_amdgcn_s_setprio(1);
#pragma unroll
    for (int c = 0; c < 4; ++c) {
      short8 ka = *(const short8*)&Ksm[cur][l31 * 64 + (((c * 2 + hi) ^ (l31 & 7)) * 8)];
      s0 = __builtin_amdgcn_mfma_f32_32x32x16_bf16(ka, qf[c], s0, 0, 0, 0);
      int r1 = 32 + l31;
      short8 kb2 = *(const short8*)&Ksm[cur][r1 * 64 + (((c * 2 + hi) ^ (r1 & 7)) * 8)];
      s1 = __builtin_amdgcn_mfma_f32_32x32x16_bf16(kb2, qf[c], s1, 0, 0, 0);
    }
    __builtin_amdgcn_s_setprio(0);
    float lsum = 0.f;
#pragma unroll
    for (int r = 0; r < 16; ++r) {
      s0[r] = __builtin_amdgcn_exp2f(s0[r]);
      s1[r] = __builtin_amdgcn_exp2f(s1[r]);
      lsum += s0[r] + s1[r];
    }
    lrun += lsum;
    unsigned int W[16];
#pragma unroll
    for (int i = 0; i < 8; ++i) {
      W[i] = pk2(s0[2 * i], s0[2 * i + 1]);
      W[8 + i] = pk2(s1[2 * i], s1[2 * i + 1]);
    }
    short8 pf[4];
#pragma unroll
    for (int c = 0; c < 4; ++c) {
      unsigned int a0 = W[4 * c + 0], b0 = W[4 * c + 2];
      unsigned int a1 = W[4 * c + 1], b1 = W[4 * c + 3];
      asm volatile("v_permlane32_swap_b32 %0, %1" : "+v"(a0), "+v"(b0));
      asm volatile("v_permlane32_swap_b32 %0, %1" : "+v"(a1), "+v"(b1));
      pf[c] = mk_frag(a0, a1, b0, b1);
    }
    __builtin_amdgcn_s_setprio(1);
#pragma unroll
    for (int c = 0; c < 4; ++c) {
      short8 va = *(const short8*)&Vsm[cur][l31 * 64 + (((c * 2 + hi) ^ (l31 & 7)) * 8)];
      oL = __builtin_amdgcn_mfma_f32_32x32x16_bf16(va, pf[c], oL, 0, 0, 0);
      int rH = 32 + l31;
      short8 vb = *(const short8*)&Vsm[cur][rH * 64 + (((c * 2 + hi) ^ (rH & 7)) * 8)];
      oH = __builtin_amdgcn_mfma_f32_32x32x16_bf16(vb, pf[c], oH, 0, 0, 0);
    }
    __builtin_amdgcn_s_setprio(0);
    __syncthreads();
    cur ^= 1;
  }
  lrun += __shfl_xor(lrun, 32, 64);
  float inv = 1.f / lrun;
  unsigned short* obp = ob + ((size_t)(bb * N + q)) * 1024 + h * 64;
#pragma unroll
  for (int r4 = 0; r4 < 4; ++r4) {
    ush4 vL, vH;
#pragma unroll
    for (int i = 0; i < 4; ++i) {
      vL[i] = f2bf(oL[r4 * 4 + i] * inv);
      vH[i] = f2bf(oH[r4 * 4 + i] * inv);
    }
    *(ush4*)&obp[r4 * 8 + hi * 4] = vL;
    *(ush4*)&obp[32 + r4 * 8 + hi * 4] = vH;
  }
}

extern "C" void kernel_launch(void* const* d_in, const int* in_sizes, int n_in,
                              void* d_out, int out_size, void* d_ws, size_t ws_size,
                              hipStream_t stream) {
  const float* x = (const float*)d_in[0];
  const float* w_qkv = (const float*)d_in[1];
  const float* w_out = (const float*)d_in[2];
  float* out = (float*)d_out;
  char* ws = (char*)d_ws;

  unsigned short* wqkv_bf = (unsigned short*)ws;                    // 6 MB
  unsigned short* wout_bf = (unsigned short*)(ws + 6291456);        // 2 MB
  unsigned short* xt      = (unsigned short*)(ws + 8388608);        // 8 MB (reused as obuf)
  unsigned short* qkbuf   = (unsigned short*)(ws + 16777216);       // 16 MB
  unsigned short* vtbuf   = (unsigned short*)(ws + 33554432);       // 8 MB
  float2* tab             = (float2*)(ws + 41943040);               // 0.5 MB

  prep_k<<<4352, 256, 0, stream>>>(w_qkv, wqkv_bf, w_out, wout_bf, tab);
  transpose_x<<<dim3(N / 32, D / 32, B), dim3(32, 8), 0, stream>>>(x, xt);

  gemm_bt<0><<<dim3(32, 24), 256, 0, stream>>>(xt, wqkv_bf, nullptr, qkbuf, vtbuf, tab);
  attn_kernel<<<512, 256, 0, stream>>>(qkbuf, vtbuf, xt /* obuf */);
  gemm_bt<1><<<dim3(32, 8), 256, 0, stream>>>(xt, wout_bf, out, nullptr, nullptr, nullptr);
}

// Round 11
// 127.216 us; speedup vs baseline: 1.5187x; 1.0115x over previous
//
#include <hip/hip_runtime.h>
#include <hip/hip_bf16.h>
#include <math.h>

#define B 2
#define N 2048
#define D 1024
#define H 16
#define HD 64

typedef __attribute__((ext_vector_type(8))) short short8;
typedef __attribute__((ext_vector_type(4))) float f32x4;
typedef __attribute__((ext_vector_type(16))) float f32x16;
typedef __attribute__((ext_vector_type(4))) unsigned short ush4;
typedef __attribute__((ext_vector_type(4))) unsigned int uint4v;

__device__ __forceinline__ float bf2f(unsigned short u) {
  unsigned int x = ((unsigned int)u) << 16;
  float f;
  __builtin_memcpy(&f, &x, 4);
  return f;
}
__device__ __forceinline__ unsigned short f2bf(float f) {
  unsigned int x;
  __builtin_memcpy(&x, &f, 4);
  x = x + 0x7fffu + ((x >> 16) & 1u);
  return (unsigned short)(x >> 16);
}
__device__ __forceinline__ unsigned int pk2(float lo, float hi) {
  union { __hip_bfloat162 h; unsigned int u; } cv;
  cv.h = __float22bfloat162_rn(make_float2(lo, hi));
  return cv.u;
}
__device__ __forceinline__ short8 mk_frag(unsigned int w0, unsigned int w1,
                                          unsigned int w2, unsigned int w3) {
  union { uint4v u; short8 s; } cv;
  cv.u = (uint4v){w0, w1, w2, w3};
  return cv.s;
}

// async global->LDS, 16B per lane. LDS dest linear (base + lane*16);
// swizzle lives in the per-lane GLOBAL address (m173/m201 pattern).
__device__ __forceinline__ void gload16(const unsigned short* g, unsigned short* l) {
  __builtin_amdgcn_global_load_lds(
      (const __attribute__((address_space(1))) unsigned int*)(const void*)g,
      (__attribute__((address_space(3))) unsigned int*)(void*)l, 16, 0, 0);
}

// ---------- prep: weight conversions + rope table in ONE launch ----------
__global__ void prep_k(const float* __restrict__ wqkv, unsigned short* __restrict__ wqkv_bf,
                       const float* __restrict__ wout, unsigned short* __restrict__ wout_bf,
                       float2* __restrict__ tab) {
  int blk = blockIdx.x;
  if (blk < 4096) {
    const float* src = (blk < 3072) ? wqkv : wout;
    unsigned short* dst = (blk < 3072) ? wqkv_bf : wout_bf;
    int i = (blk < 3072 ? blk : blk - 3072) * 256 + threadIdx.x;
    float4 v = ((const float4*)src)[i];
    ush4 o;
    o[0] = f2bf(v.x); o[1] = f2bf(v.y); o[2] = f2bf(v.z); o[3] = f2bf(v.w);
    *(ush4*)&dst[i * 4] = o;
  } else {
    int idx = (blk - 4096) * 256 + threadIdx.x;  // 2048*32
    int t = idx >> 5, p = idx & 31;
    float inv = powf(10000.f, -(float)p / 32.f);
    float ang = (float)t * inv;
    float s, c;
    sincosf(ang, &s, &c);
    tab[idx] = make_float2(c, s);
  }
}

// x (B, D, N) f32 -> xt (B, N, D) bf16
__global__ __launch_bounds__(256) void transpose_x(const float* __restrict__ x,
                                                   unsigned short* __restrict__ xt) {
  __shared__ float tile[32][33];
  const int tx = threadIdx.x, ty = threadIdx.y;
  const int t0 = blockIdx.x * 32, d0 = blockIdx.y * 32, bb = blockIdx.z;
#pragma unroll
  for (int i = 0; i < 4; ++i) {
    int r = ty * 4 + i;
    tile[r][tx] = x[(size_t)bb * D * N + (size_t)(d0 + r) * N + t0 + tx];
  }
  __syncthreads();
#pragma unroll
  for (int i = 0; i < 4; ++i) {
    int r = ty * 4 + i;
    xt[((size_t)(bb * N) + t0 + r) * D + d0 + tx] = f2bf(tile[tx][r]);
  }
}

// ---------- GEMM: C[m][n] = sum_k A[m][k] * Bt[n][k], both K-contiguous bf16 ----------
// 128x128 tile, BK=64, 4 waves (2x2), wave = 64x64 (4x4 fragments of 16x16x32).
// 1-D grid with reuse-shaped XCD swizzle (T1): xcd = bid&7 owns a 4m x all-n
// rectangle, m fastest -> 4 co-resident blocks per XCD share one B-panel and
// the XCD's A working set (1 MB) stays L2-hot. Bijective (grid % 8 == 0).
// MODE 0: qkv projection epilogue -> q/k token-major into qkbuf, v transposed into vtbuf.
// MODE 1: final projection epilogue -> f32 out (B, D, N).
template <int MODE>
__global__ __launch_bounds__(256) void gemm_bt(const unsigned short* __restrict__ A,
                                               const unsigned short* __restrict__ Bt,
                                               float* __restrict__ outf,
                                               unsigned short* __restrict__ qkbuf,
                                               unsigned short* __restrict__ vtbuf) {
  __shared__ unsigned short Asm[128 * 64];
  __shared__ unsigned short Bsm[128 * 64];
  const int tid = threadIdx.x;
  const int lane = tid & 63, wid = tid >> 6;
  const int ln = lane & 15, lh = lane >> 4;
  const int wr = wid >> 1, wc = wid & 1;
  // XCD-locality swizzle: m-block = xcd*4 + (j&3), n-block = j>>2
  const int bid = blockIdx.x;
  const int xcd = bid & 7, j = bid >> 3;
  const int m0 = (xcd * 4 + (j & 3)) * 128;
  const int n0 = (j >> 2) * 128;

  f32x4 acc[4][4];
#pragma unroll
  for (int i = 0; i < 4; ++i)
#pragma unroll
    for (int jq = 0; jq < 4; ++jq) acc[i][jq] = (f32x4){0.f, 0.f, 0.f, 0.f};

  for (int k0 = 0; k0 < 1024; k0 += 64) {
#pragma unroll
    for (int jj = 0; jj < 4; ++jj) {
      int slot = tid + jj * 256;
      int row = slot >> 3, u = slot & 7;
      int usw = (u ^ (row & 7)) * 8;
      gload16(&A[(size_t)(m0 + row) * 1024 + k0 + usw], &Asm[slot * 8]);
    }
#pragma unroll
    for (int jj = 0; jj < 4; ++jj) {
      int slot = tid + jj * 256;
      int row = slot >> 3, u = slot & 7;
      int usw = (u ^ (row & 7)) * 8;
      gload16(&Bt[(size_t)(n0 + row) * 1024 + k0 + usw], &Bsm[slot * 8]);
    }
    __syncthreads();
#pragma unroll
    for (int s = 0; s < 2; ++s) {
      short8 af[4], bfr[4];
#pragma unroll
      for (int i = 0; i < 4; ++i) {
        int row = wr * 64 + i * 16 + ln;
        int u = ((s * 4 + lh) ^ (row & 7)) * 8;
        af[i] = *(const short8*)&Asm[row * 64 + u];
      }
#pragma unroll
      for (int jq = 0; jq < 4; ++jq) {
        int row = wc * 64 + jq * 16 + ln;
        int u = ((s * 4 + lh) ^ (row & 7)) * 8;
        bfr[jq] = *(const short8*)&Bsm[row * 64 + u];
      }
#pragma unroll
      for (int i = 0; i < 4; ++i)
#pragma unroll
        for (int jq = 0; jq < 4; ++jq)
          acc[i][jq] = __builtin_amdgcn_mfma_f32_16x16x32_bf16(af[i], bfr[jq], acc[i][jq], 0, 0, 0);
    }
    __syncthreads();
  }

#pragma unroll
  for (int i = 0; i < 4; ++i) {
    int mrow = m0 + wr * 64 + i * 16 + lh * 4;
    int bb = mrow >> 11, t = mrow & 2047;
#pragma unroll
    for (int jq = 0; jq < 4; ++jq) {
      int e = n0 + wc * 64 + jq * 16 + ln;
      if (MODE == 1) {
        float* op = outf + (size_t)bb * D * N + (size_t)e * N + t;
        *(f32x4*)op = acc[i][jq];
      } else {
        if (e < 2048) {
#pragma unroll
          for (int jj = 0; jj < 4; ++jj)
            qkbuf[((size_t)(bb * N + t + jj)) * 2048 + e] = f2bf(acc[i][jq][jj]);
        } else {
          ush4 v;
#pragma unroll
          for (int jj = 0; jj < 4; ++jj) v[jj] = f2bf(acc[i][jq][jj]);
          *(ush4*)&vtbuf[((size_t)bb * 1024 + (e - 2048)) * N + t] = v;
        }
      }
    }
  }
}

// ---------- RoPE in place on qkbuf (B, N, 2048) bf16, pairs adjacent ----------
// Folds 0.125*log2e into the q section so attention uses exp2 with no scaling.
__global__ void rope_kernel(unsigned short* __restrict__ qk, const float2* __restrict__ tab) {
  int idx = blockIdx.x * 256 + threadIdx.x;  // B*N*2048/8 = 1,048,576
  int e = (idx & 255) * 8;
  int t = (idx >> 8) & 2047;
  int bb = idx >> 19;
  int p0 = (e & 63) >> 1;
  const float qscl = 0.125f * 1.4426950408889634f;  // hd^-0.5 * log2(e)
  float sc = (e < 1024) ? qscl : 1.0f;
  unsigned short* p = qk + ((size_t)(bb * N + t)) * 2048 + e;
  short8 v = *(short8*)p;
#pragma unroll
  for (int q = 0; q < 4; ++q) {
    float2 cs = tab[t * 32 + p0 + q];
    float xe = bf2f((unsigned short)v[2 * q]);
    float xo = bf2f((unsigned short)v[2 * q + 1]);
    v[2 * q] = (short)f2bf((xe * cs.x - xo * cs.y) * sc);
    v[2 * q + 1] = (short)f2bf((xe * cs.y + xo * cs.x) * sc);
  }
  *(short8*)p = v;
}

// ---------- flash attention: swapped-operand 32x32 MFMA, P in registers ----------
// STATIC-MAX softmax (logits bounded; P = exp2(s) directly, l a plain sum).
// R4 structure verbatim (proven 55.4 us): 2-buf LDS, one syncthreads/iter.
// qk: (B, N, 2048) bf16 (q pre-scaled by 0.125*log2e); vt: (B, 1024, N) bf16.
__global__ __launch_bounds__(256, 2) void attn_kernel(const unsigned short* __restrict__ qk,
                                                      const unsigned short* __restrict__ vt,
                                                      unsigned short* __restrict__ ob) {
  __shared__ unsigned short Ksm[2][64 * 64];  // [key][d]
  __shared__ unsigned short Vsm[2][64 * 64];  // [d][key]
  const int tid = threadIdx.x;
  const int lane = tid & 63, wid = tid >> 6;
  const int l31 = lane & 31, hi = lane >> 5;
  const int L = blockIdx.x;
  const int hh = L & 31, qb = L >> 5;
  const int bb = hh >> 4, h = hh & 15;
  const unsigned short* Qg = qk + (size_t)bb * N * 2048 + h * 64;
  const unsigned short* Kg = Qg + 1024;
  const unsigned short* Vg = vt + ((size_t)bb * 1024 + h * 64) * N;

  const int q = qb * 128 + wid * 32 + l31;
  short8 qf[4];
#pragma unroll
  for (int c = 0; c < 4; ++c)
    qf[c] = *(const short8*)&Qg[(size_t)q * 2048 + c * 16 + hi * 8];

  f32x16 oL, oH;
#pragma unroll
  for (int r = 0; r < 16; ++r) { oL[r] = 0.f; oH[r] = 0.f; }
  float lrun = 0.f;

  auto STAGE = [&](int buf, int kb) {
#pragma unroll
    for (int jj = 0; jj < 2; ++jj) {
      int slot = tid + jj * 256;
      int row = slot >> 3, u = slot & 7;
      int usw = (u ^ (row & 7)) * 8;
      gload16(&Kg[(size_t)(kb + row) * 2048 + usw], &Ksm[buf][slot * 8]);
    }
#pragma unroll
    for (int jj = 0; jj < 2; ++jj) {
      int slot = tid + jj * 256;
      int row = slot >> 3, u = slot & 7;
      int usw = (u ^ (row & 7)) * 8;
      gload16(&Vg[(size_t)row * N + kb + usw], &Vsm[buf][slot * 8]);
    }
  };

  STAGE(0, 0);
  __syncthreads();
  int cur = 0;
  for (int t = 0; t < N / 64; ++t) {
    if (t < N / 64 - 1) STAGE(cur ^ 1, (t + 1) * 64);
    f32x16 s0, s1;
#pragma unroll
    for (int r = 0; r < 16; ++r) { s0[r] = 0.f; s1[r] = 0.f; }
    __builtin_amdgcn_s_setprio(1);
#pragma unroll
    for (int c = 0; c < 4; ++c) {
      short8 ka = *(const short8*)&Ksm[cur][l31 * 64 + (((c * 2 + hi) ^ (l31 & 7)) * 8)];
      s0 = __builtin_amdgcn_mfma_f32_32x32x16_bf16(ka, qf[c], s0, 0, 0, 0);
      int r1 = 32 + l31;
      short8 kb2 = *(const short8*)&Ksm[cur][r1 * 64 + (((c * 2 + hi) ^ (r1 & 7)) * 8)];
      s1 = __builtin_amdgcn_mfma_f32_32x32x16_bf16(kb2, qf[c], s1, 0, 0, 0);
    }
    __builtin_amdgcn_s_setprio(0);
    float lsum = 0.f;
#pragma unroll
    for (int r = 0; r < 16; ++r) {
      s0[r] = __builtin_amdgcn_exp2f(s0[r]);
      s1[r] = __builtin_amdgcn_exp2f(s1[r]);
      lsum += s0[r] + s1[r];
    }
    lrun += lsum;
    unsigned int W[16];
#pragma unroll
    for (int i = 0; i < 8; ++i) {
      W[i] = pk2(s0[2 * i], s0[2 * i + 1]);
      W[8 + i] = pk2(s1[2 * i], s1[2 * i + 1]);
    }
    short8 pf[4];
#pragma unroll
    for (int c = 0; c < 4; ++c) {
      unsigned int a0 = W[4 * c + 0], b0 = W[4 * c + 2];
      unsigned int a1 = W[4 * c + 1], b1 = W[4 * c + 3];
      asm volatile("v_permlane32_swap_b32 %0, %1" : "+v"(a0), "+v"(b0));
      asm volatile("v_permlane32_swap_b32 %0, %1" : "+v"(a1), "+v"(b1));
      pf[c] = mk_frag(a0, a1, b0, b1);
    }
    __builtin_amdgcn_s_setprio(1);
#pragma unroll
    for (int c = 0; c < 4; ++c) {
      short8 va = *(const short8*)&Vsm[cur][l31 * 64 + (((c * 2 + hi) ^ (l31 & 7)) * 8)];
      oL = __builtin_amdgcn_mfma_f32_32x32x16_bf16(va, pf[c], oL, 0, 0, 0);
      int rH = 32 + l31;
      short8 vb = *(const short8*)&Vsm[cur][rH * 64 + (((c * 2 + hi) ^ (rH & 7)) * 8)];
      oH = __builtin_amdgcn_mfma_f32_32x32x16_bf16(vb, pf[c], oH, 0, 0, 0);
    }
    __builtin_amdgcn_s_setprio(0);
    __syncthreads();
    cur ^= 1;
  }
  lrun += __shfl_xor(lrun, 32, 64);
  float inv = 1.f / lrun;
  unsigned short* obp = ob + ((size_t)(bb * N + q)) * 1024 + h * 64;
#pragma unroll
  for (int r4 = 0; r4 < 4; ++r4) {
    ush4 vL, vH;
#pragma unroll
    for (int i = 0; i < 4; ++i) {
      vL[i] = f2bf(oL[r4 * 4 + i] * inv);
      vH[i] = f2bf(oH[r4 * 4 + i] * inv);
    }
    *(ush4*)&obp[r4 * 8 + hi * 4] = vL;
    *(ush4*)&obp[32 + r4 * 8 + hi * 4] = vH;
  }
}

extern "C" void kernel_launch(void* const* d_in, const int* in_sizes, int n_in,
                              void* d_out, int out_size, void* d_ws, size_t ws_size,
                              hipStream_t stream) {
  const float* x = (const float*)d_in[0];
  const float* w_qkv = (const float*)d_in[1];
  const float* w_out = (const float*)d_in[2];
  float* out = (float*)d_out;
  char* ws = (char*)d_ws;

  unsigned short* wqkv_bf = (unsigned short*)ws;                    // 6 MB
  unsigned short* wout_bf = (unsigned short*)(ws + 6291456);        // 2 MB
  unsigned short* xt      = (unsigned short*)(ws + 8388608);        // 8 MB (reused as obuf)
  unsigned short* qkbuf   = (unsigned short*)(ws + 16777216);       // 16 MB
  unsigned short* vtbuf   = (unsigned short*)(ws + 33554432);       // 8 MB
  float2* tab             = (float2*)(ws + 41943040);               // 0.5 MB

  prep_k<<<4352, 256, 0, stream>>>(w_qkv, wqkv_bf, w_out, wout_bf, tab);
  transpose_x<<<dim3(N / 32, D / 32, B), dim3(32, 8), 0, stream>>>(x, xt);

  gemm_bt<0><<<768, 256, 0, stream>>>(xt, wqkv_bf, nullptr, qkbuf, vtbuf);
  rope_kernel<<<4096, 256, 0, stream>>>(qkbuf, tab);
  attn_kernel<<<512, 256, 0, stream>>>(qkbuf, vtbuf, xt /* obuf */);
  gemm_bt<1><<<256, 256, 0, stream>>>(xt, wout_bf, out, nullptr, nullptr);
}

// Round 12
// 126.584 us; speedup vs baseline: 1.5263x; 1.0050x over previous
//
#include <hip/hip_runtime.h>
#include <hip/hip_bf16.h>
#include <math.h>

#define B 2
#define N 2048
#define D 1024
#define H 16
#define HD 64

typedef __attribute__((ext_vector_type(8))) short short8;
typedef __attribute__((ext_vector_type(4))) float f32x4;
typedef __attribute__((ext_vector_type(16))) float f32x16;
typedef __attribute__((ext_vector_type(4))) unsigned short ush4;
typedef __attribute__((ext_vector_type(4))) unsigned int uint4v;

__device__ __forceinline__ float bf2f(unsigned short u) {
  unsigned int x = ((unsigned int)u) << 16;
  float f;
  __builtin_memcpy(&f, &x, 4);
  return f;
}
__device__ __forceinline__ unsigned short f2bf(float f) {
  unsigned int x;
  __builtin_memcpy(&x, &f, 4);
  x = x + 0x7fffu + ((x >> 16) & 1u);
  return (unsigned short)(x >> 16);
}
__device__ __forceinline__ unsigned int pk2(float lo, float hi) {
  union { __hip_bfloat162 h; unsigned int u; } cv;
  cv.h = __float22bfloat162_rn(make_float2(lo, hi));
  return cv.u;
}
__device__ __forceinline__ short8 mk_frag(unsigned int w0, unsigned int w1,
                                          unsigned int w2, unsigned int w3) {
  union { uint4v u; short8 s; } cv;
  cv.u = (uint4v){w0, w1, w2, w3};
  return cv.s;
}

// async global->LDS, 16B per lane. LDS dest linear (base + lane*16);
// swizzle lives in the per-lane GLOBAL address (m173/m201 pattern).
__device__ __forceinline__ void gload16(const unsigned short* g, unsigned short* l) {
  __builtin_amdgcn_global_load_lds(
      (const __attribute__((address_space(1))) unsigned int*)(const void*)g,
      (__attribute__((address_space(3))) unsigned int*)(void*)l, 16, 0, 0);
}

// ---------- prep: weight conversions + rope table in ONE launch ----------
__global__ void prep_k(const float* __restrict__ wqkv, unsigned short* __restrict__ wqkv_bf,
                       const float* __restrict__ wout, unsigned short* __restrict__ wout_bf,
                       float2* __restrict__ tab) {
  int blk = blockIdx.x;
  if (blk < 4096) {
    const float* src = (blk < 3072) ? wqkv : wout;
    unsigned short* dst = (blk < 3072) ? wqkv_bf : wout_bf;
    int i = (blk < 3072 ? blk : blk - 3072) * 256 + threadIdx.x;
    float4 v = ((const float4*)src)[i];
    ush4 o;
    o[0] = f2bf(v.x); o[1] = f2bf(v.y); o[2] = f2bf(v.z); o[3] = f2bf(v.w);
    *(ush4*)&dst[i * 4] = o;
  } else {
    int idx = (blk - 4096) * 256 + threadIdx.x;  // 2048*32
    int t = idx >> 5, p = idx & 31;
    float inv = powf(10000.f, -(float)p / 32.f);
    float ang = (float)t * inv;
    float s, c;
    sincosf(ang, &s, &c);
    tab[idx] = make_float2(c, s);
  }
}

// x (B, D, N) f32 -> xt (B, N, D) bf16
__global__ __launch_bounds__(256) void transpose_x(const float* __restrict__ x,
                                                   unsigned short* __restrict__ xt) {
  __shared__ float tile[32][33];
  const int tx = threadIdx.x, ty = threadIdx.y;
  const int t0 = blockIdx.x * 32, d0 = blockIdx.y * 32, bb = blockIdx.z;
#pragma unroll
  for (int i = 0; i < 4; ++i) {
    int r = ty * 4 + i;
    tile[r][tx] = x[(size_t)bb * D * N + (size_t)(d0 + r) * N + t0 + tx];
  }
  __syncthreads();
#pragma unroll
  for (int i = 0; i < 4; ++i) {
    int r = ty * 4 + i;
    xt[((size_t)(bb * N) + t0 + r) * D + d0 + tx] = f2bf(tile[tx][r]);
  }
}

// ---------- GEMM: C[m][n] = sum_k A[m][k] * Bt[n][k], both K-contiguous bf16 ----------
// 128x128 tile, BK=64, 4 waves (2x2). XCD-locality swizzle (R11).
// MODE 0: qkv projection epilogue -> q/k token-major (UNroped; q unscaled),
//         v transposed into vtbuf. MODE 1: final projection -> f32 out (B,D,N).
template <int MODE>
__global__ __launch_bounds__(256) void gemm_bt(const unsigned short* __restrict__ A,
                                               const unsigned short* __restrict__ Bt,
                                               float* __restrict__ outf,
                                               unsigned short* __restrict__ qkbuf,
                                               unsigned short* __restrict__ vtbuf) {
  __shared__ unsigned short Asm[128 * 64];
  __shared__ unsigned short Bsm[128 * 64];
  const int tid = threadIdx.x;
  const int lane = tid & 63, wid = tid >> 6;
  const int ln = lane & 15, lh = lane >> 4;
  const int wr = wid >> 1, wc = wid & 1;
  const int bid = blockIdx.x;
  const int xcd = bid & 7, j = bid >> 3;
  const int m0 = (xcd * 4 + (j & 3)) * 128;
  const int n0 = (j >> 2) * 128;

  f32x4 acc[4][4];
#pragma unroll
  for (int i = 0; i < 4; ++i)
#pragma unroll
    for (int jq = 0; jq < 4; ++jq) acc[i][jq] = (f32x4){0.f, 0.f, 0.f, 0.f};

  for (int k0 = 0; k0 < 1024; k0 += 64) {
#pragma unroll
    for (int jj = 0; jj < 4; ++jj) {
      int slot = tid + jj * 256;
      int row = slot >> 3, u = slot & 7;
      int usw = (u ^ (row & 7)) * 8;
      gload16(&A[(size_t)(m0 + row) * 1024 + k0 + usw], &Asm[slot * 8]);
    }
#pragma unroll
    for (int jj = 0; jj < 4; ++jj) {
      int slot = tid + jj * 256;
      int row = slot >> 3, u = slot & 7;
      int usw = (u ^ (row & 7)) * 8;
      gload16(&Bt[(size_t)(n0 + row) * 1024 + k0 + usw], &Bsm[slot * 8]);
    }
    __syncthreads();
#pragma unroll
    for (int s = 0; s < 2; ++s) {
      short8 af[4], bfr[4];
#pragma unroll
      for (int i = 0; i < 4; ++i) {
        int row = wr * 64 + i * 16 + ln;
        int u = ((s * 4 + lh) ^ (row & 7)) * 8;
        af[i] = *(const short8*)&Asm[row * 64 + u];
      }
#pragma unroll
      for (int jq = 0; jq < 4; ++jq) {
        int row = wc * 64 + jq * 16 + ln;
        int u = ((s * 4 + lh) ^ (row & 7)) * 8;
        bfr[jq] = *(const short8*)&Bsm[row * 64 + u];
      }
#pragma unroll
      for (int i = 0; i < 4; ++i)
#pragma unroll
        for (int jq = 0; jq < 4; ++jq)
          acc[i][jq] = __builtin_amdgcn_mfma_f32_16x16x32_bf16(af[i], bfr[jq], acc[i][jq], 0, 0, 0);
    }
    __syncthreads();
  }

#pragma unroll
  for (int i = 0; i < 4; ++i) {
    int mrow = m0 + wr * 64 + i * 16 + lh * 4;
    int bb = mrow >> 11, t = mrow & 2047;
#pragma unroll
    for (int jq = 0; jq < 4; ++jq) {
      int e = n0 + wc * 64 + jq * 16 + ln;
      if (MODE == 1) {
        float* op = outf + (size_t)bb * D * N + (size_t)e * N + t;
        *(f32x4*)op = acc[i][jq];
      } else {
        if (e < 2048) {
#pragma unroll
          for (int jj = 0; jj < 4; ++jj)
            qkbuf[((size_t)(bb * N + t + jj)) * 2048 + e] = f2bf(acc[i][jq][jj]);
        } else {
          ush4 v;
#pragma unroll
          for (int jj = 0; jj < 4; ++jj) v[jj] = f2bf(acc[i][jq][jj]);
          *(ush4*)&vtbuf[((size_t)bb * 1024 + (e - 2048)) * N + t] = v;
        }
      }
    }
  }
}

// ---------- RoPE: K section only (Q-rope is folded into attn's Q load) ----------
__global__ void rope_kernel(unsigned short* __restrict__ qk, const float2* __restrict__ tab) {
  int idx = blockIdx.x * 256 + threadIdx.x;  // B*N*1024/8 = 524,288
  int e = 1024 + (idx & 127) * 8;
  int t = (idx >> 7) & 2047;
  int bb = idx >> 18;
  int p0 = (e & 63) >> 1;
  unsigned short* p = qk + ((size_t)(bb * N + t)) * 2048 + e;
  short8 v = *(short8*)p;
#pragma unroll
  for (int q = 0; q < 4; ++q) {
    float2 cs = tab[t * 32 + p0 + q];
    float xe = bf2f((unsigned short)v[2 * q]);
    float xo = bf2f((unsigned short)v[2 * q + 1]);
    v[2 * q] = (short)f2bf(xe * cs.x - xo * cs.y);
    v[2 * q + 1] = (short)f2bf(xe * cs.y + xo * cs.x);
  }
  *(short8*)p = v;
}

// ---------- flash attention: 128-key tiles, raw barriers + counted vmcnt ----------
// STATIC-MAX softmax (P = exp2(s), l plain sum). Per iter: two 64-key compute
// halves in ONE barrier region; 2-buf of 128-key tiles (64 KB LDS, 2 blk/CU);
// raw s_barrier + vmcnt(8) (= 8 gload/wave/tile) instead of full drains.
// Q-rope + 0.125*log2e scale applied at the one-time Q load (tab lookups).
// qk: (B,N,2048) bf16 RAW; vt: (B,1024,N) bf16; ob: (B,N,1024) bf16.
__global__ __launch_bounds__(256, 2) void attn_kernel(const unsigned short* __restrict__ qk,
                                                      const unsigned short* __restrict__ vt,
                                                      unsigned short* __restrict__ ob,
                                                      const float2* __restrict__ tab) {
  __shared__ unsigned short Ksm[2][128 * 64];  // [key][d] swizzled, 16 KB each
  __shared__ unsigned short Vsm[2][64 * 128];  // [d][key] swizzled, 16 KB each
  const int tid = threadIdx.x;
  const int lane = tid & 63, wid = tid >> 6;
  const int l31 = lane & 31, hi = lane >> 5;
  const int L = blockIdx.x;
  const int hh = L & 31, qb = L >> 5;
  const int bb = hh >> 4, h = hh & 15;
  const unsigned short* Qg = qk + (size_t)bb * N * 2048 + h * 64;
  const unsigned short* Kg = Qg + 1024;
  const unsigned short* Vg = vt + ((size_t)bb * 1024 + h * 64) * N;

  const int q = qb * 128 + wid * 32 + l31;
  // Q B-fragments with FUSED RoPE + scale: d = c*16 + hi*8 + j, pairs adjacent.
  const float qscl = 0.125f * 1.4426950408889634f;  // hd^-0.5 * log2(e)
  short8 qf[4];
#pragma unroll
  for (int c = 0; c < 4; ++c) {
    short8 raw = *(const short8*)&Qg[(size_t)q * 2048 + c * 16 + hi * 8];
    short8 f;
#pragma unroll
    for (int pp = 0; pp < 4; ++pp) {
      float2 cs = tab[q * 32 + c * 8 + hi * 4 + pp];
      float xe = bf2f((unsigned short)raw[2 * pp]);
      float xo = bf2f((unsigned short)raw[2 * pp + 1]);
      f[2 * pp] = (short)f2bf((xe * cs.x - xo * cs.y) * qscl);
      f[2 * pp + 1] = (short)f2bf((xe * cs.y + xo * cs.x) * qscl);
    }
    qf[c] = f;
  }

  f32x16 z16;
#pragma unroll
  for (int r = 0; r < 16; ++r) z16[r] = 0.f;
  f32x16 oL = z16, oH = z16;
  float lrun = 0.f;

  // STAGE one 128-key tile: K [128 rows][64 d] (8 x 16B units/row, u^(row&7));
  // V [64 d-rows][128 keys] (16 units/row, u^(row&15)). 8 gload/thread.
  auto STAGE = [&](int buf, int kb) {
#pragma unroll
    for (int jj = 0; jj < 4; ++jj) {
      int slot = tid + jj * 256;
      int row = slot >> 3, u = slot & 7;
      int usw = (u ^ (row & 7)) * 8;
      gload16(&Kg[(size_t)(kb + row) * 2048 + usw], &Ksm[buf][slot * 8]);
    }
#pragma unroll
    for (int jj = 0; jj < 4; ++jj) {
      int slot = tid + jj * 256;
      int row = slot >> 4, u = slot & 15;
      int usw = (u ^ (row & 15)) * 8;
      gload16(&Vg[(size_t)row * N + kb + usw], &Vsm[buf][slot * 8]);
    }
  };

  // one 64-key half: h2 selects keys [h2*64, h2*64+64) within the 128-key tile
  auto COMPUTE64 = [&](const unsigned short* Kb, const unsigned short* Vb, int h2) {
    const int r0 = h2 * 64 + l31, r1 = h2 * 64 + 32 + l31;
    f32x16 s0, s1;
    {
      short8 ka = *(const short8*)&Kb[r0 * 64 + (((0 + hi) ^ (r0 & 7)) * 8)];
      s0 = __builtin_amdgcn_mfma_f32_32x32x16_bf16(ka, qf[0], z16, 0, 0, 0);
      short8 kc = *(const short8*)&Kb[r1 * 64 + (((0 + hi) ^ (r1 & 7)) * 8)];
      s1 = __builtin_amdgcn_mfma_f32_32x32x16_bf16(kc, qf[0], z16, 0, 0, 0);
    }
#pragma unroll
    for (int c = 1; c < 4; ++c) {
      short8 ka = *(const short8*)&Kb[r0 * 64 + (((c * 2 + hi) ^ (r0 & 7)) * 8)];
      s0 = __builtin_amdgcn_mfma_f32_32x32x16_bf16(ka, qf[c], s0, 0, 0, 0);
      short8 kc = *(const short8*)&Kb[r1 * 64 + (((c * 2 + hi) ^ (r1 & 7)) * 8)];
      s1 = __builtin_amdgcn_mfma_f32_32x32x16_bf16(kc, qf[c], s1, 0, 0, 0);
    }
    float lsum = 0.f;
#pragma unroll
    for (int r = 0; r < 16; ++r) {
      s0[r] = __builtin_amdgcn_exp2f(s0[r]);
      s1[r] = __builtin_amdgcn_exp2f(s1[r]);
      lsum += s0[r] + s1[r];
    }
    lrun += lsum;
    unsigned int W[16];
#pragma unroll
    for (int i = 0; i < 8; ++i) {
      W[i] = pk2(s0[2 * i], s0[2 * i + 1]);
      W[8 + i] = pk2(s1[2 * i], s1[2 * i + 1]);
    }
    short8 pf[4];
#pragma unroll
    for (int c = 0; c < 4; ++c) {
      unsigned int a0 = W[4 * c + 0], b0 = W[4 * c + 2];
      unsigned int a1 = W[4 * c + 1], b1 = W[4 * c + 3];
      asm volatile("v_permlane32_swap_b32 %0, %1" : "+v"(a0), "+v"(b0));
      asm volatile("v_permlane32_swap_b32 %0, %1" : "+v"(a1), "+v"(b1));
      pf[c] = mk_frag(a0, a1, b0, b1);
    }
    const int vA = l31, vB = 32 + l31;
#pragma unroll
    for (int c = 0; c < 4; ++c) {
      int ua = ((h2 * 8 + c * 2 + hi) ^ (vA & 15)) * 8;
      short8 va = *(const short8*)&Vb[vA * 128 + ua];
      oL = __builtin_amdgcn_mfma_f32_32x32x16_bf16(va, pf[c], oL, 0, 0, 0);
      int ub = ((h2 * 8 + c * 2 + hi) ^ (vB & 15)) * 8;
      short8 vb = *(const short8*)&Vb[vB * 128 + ub];
      oH = __builtin_amdgcn_mfma_f32_32x32x16_bf16(vb, pf[c], oH, 0, 0, 0);
    }
  };

  STAGE(0, 0);
  int cur = 0;
  for (int t = 0; t < 16; ++t) {
    __builtin_amdgcn_sched_barrier(0);
    __builtin_amdgcn_s_barrier();                      // prev compute done -> cur^1 free
    if (t < 15) {
      STAGE(cur ^ 1, (t + 1) * 128);
      asm volatile("s_waitcnt vmcnt(8)" ::: "memory"); // my tile-t loads landed
    } else {
      asm volatile("s_waitcnt vmcnt(0)" ::: "memory");
    }
    __builtin_amdgcn_sched_barrier(0);
    __builtin_amdgcn_s_barrier();                      // tile t published
    __builtin_amdgcn_s_setprio(1);
    COMPUTE64(Ksm[cur], Vsm[cur], 0);
    COMPUTE64(Ksm[cur], Vsm[cur], 1);
    __builtin_amdgcn_s_setprio(0);
    cur ^= 1;
  }

  lrun += __shfl_xor(lrun, 32, 64);
  float inv = 1.f / lrun;
  unsigned short* obp = ob + ((size_t)(bb * N + q)) * 1024 + h * 64;
#pragma unroll
  for (int r4 = 0; r4 < 4; ++r4) {
    ush4 vL, vH;
#pragma unroll
    for (int i = 0; i < 4; ++i) {
      vL[i] = f2bf(oL[r4 * 4 + i] * inv);
      vH[i] = f2bf(oH[r4 * 4 + i] * inv);
    }
    *(ush4*)&obp[r4 * 8 + hi * 4] = vL;
    *(ush4*)&obp[32 + r4 * 8 + hi * 4] = vH;
  }
}

extern "C" void kernel_launch(void* const* d_in, const int* in_sizes, int n_in,
                              void* d_out, int out_size, void* d_ws, size_t ws_size,
                              hipStream_t stream) {
  const float* x = (const float*)d_in[0];
  const float* w_qkv = (const float*)d_in[1];
  const float* w_out = (const float*)d_in[2];
  float* out = (float*)d_out;
  char* ws = (char*)d_ws;

  unsigned short* wqkv_bf = (unsigned short*)ws;                    // 6 MB
  unsigned short* wout_bf = (unsigned short*)(ws + 6291456);        // 2 MB
  unsigned short* xt      = (unsigned short*)(ws + 8388608);        // 8 MB (reused as obuf)
  unsigned short* qkbuf   = (unsigned short*)(ws + 16777216);       // 16 MB
  unsigned short* vtbuf   = (unsigned short*)(ws + 33554432);       // 8 MB
  float2* tab             = (float2*)(ws + 41943040);               // 0.5 MB

  prep_k<<<4352, 256, 0, stream>>>(w_qkv, wqkv_bf, w_out, wout_bf, tab);
  transpose_x<<<dim3(N / 32, D / 32, B), dim3(32, 8), 0, stream>>>(x, xt);

  gemm_bt<0><<<768, 256, 0, stream>>>(xt, wqkv_bf, nullptr, qkbuf, vtbuf);
  rope_kernel<<<2048, 256, 0, stream>>>(qkbuf, tab);
  attn_kernel<<<512, 256, 0, stream>>>(qkbuf, vtbuf, xt /* obuf */, tab);
  gemm_bt<1><<<256, 256, 0, stream>>>(xt, wout_bf, out, nullptr, nullptr);
}